// Round 14
// baseline (3204.284 us; speedup 1.0000x reference)
//
#include <hip/hip_runtime.h>

typedef unsigned short u16t;
typedef __attribute__((ext_vector_type(8))) short bf16x8;
typedef __attribute__((ext_vector_type(4))) float f32x4;
typedef __attribute__((ext_vector_type(2))) float f32x2;

#define DI static __device__ __forceinline__

constexpr int Bn = 256, Tn = 512;
constexpr long Rn = (long)Bn * Tn;   // 131072 rows = (b,t) pairs

DI float b2f(u16t u){ union{unsigned u32; float f;} v; v.u32 = ((unsigned)u)<<16; return v.f; }
DI u16t f2b(float f){ union{float fp; unsigned u;} v; v.fp=f; return (u16t)((v.u + 0x7fffu + ((v.u>>16)&1u))>>16); }
DI float fsigm(float x){ return __builtin_amdgcn_rcpf(1.f + __expf(-x)); }
DI float ftanh(float x){ float e = __expf(2.f*x); return 1.f - 2.f*__builtin_amdgcn_rcpf(e+1.f); }
DI float fgelu(float x){
  float t = 0.7978845608028654f*x*(1.f + 0.044715f*x*x);
  return x*(1.f - __builtin_amdgcn_rcpf(__expf(2.f*t)+1.f));
}
DI f32x4 mfma16(bf16x8 a, bf16x8 b, f32x4 c){ return __builtin_amdgcn_mfma_f32_16x16x32_bf16(a,b,c,0,0,0); }
// HW packed convert (RNE): dst = {bf16(b)<<16 | bf16(a)}  [T12 primitive, m214v22]
DI unsigned cvtpk(float a, float b){
  unsigned r;
  asm("v_cvt_pk_bf16_f32 %0, %1, %2" : "=v"(r) : "v"(a), "v"(b));
  return r;
}
DI bf16x8 mk8(unsigned w0,unsigned w1,unsigned w2,unsigned w3){
  union{unsigned u[4]; bf16x8 v;} z; z.u[0]=w0; z.u[1]=w1; z.u[2]=w2; z.u[3]=w3; return z.v;
}
// load 8 consecutive fp32 -> bf16x8 (RNE via cvt_pk: 4 VALU)
DI bf16x8 ldw8(const float* p){
  f32x4 a = *(const f32x4*)p, b = *(const f32x4*)(p+4);
  return mk8(cvtpk(a[0],a[1]), cvtpk(a[2],a[3]), cvtpk(b[0],b[1]), cvtpk(b[2],b[3]));
}
DI bf16x8 zero8(){ bf16x8 v; v[0]=0;v[1]=0;v[2]=0;v[3]=0;v[4]=0;v[5]=0;v[6]=0;v[7]=0; return v; }
// single-wave LDS fence: order LDS writes->reads without draining vmcnt
DI void lfence(){ asm volatile("s_waitcnt lgkmcnt(0)" ::: "memory"); __builtin_amdgcn_sched_barrier(0); }

// ---------------- K1: MFMA pre-pass, 64 rows/block ----------------
__global__ __launch_bounds__(256) void k_pre(
    const float* __restrict__ states, const float* __restrict__ nfast,
    const float* __restrict__ fe_w1, const float* __restrict__ fe_b1,
    const float* __restrict__ fe_w2, const float* __restrict__ fe_b2,
    const float* __restrict__ se_w1, const float* __restrict__ se_b1,
    u16t* __restrict__ ws_zfn, u16t* __restrict__ ws_se1)
{
  __shared__ __align__(16) u16t s_x[64*256];
  __shared__ __align__(16) u16t s_h[64*256];
  const int tid = threadIdx.x;
  const int lane = tid & 63, wave = tid >> 6;
  const int l15 = lane & 15, lh = lane >> 4;
  const long row0 = (long)blockIdx.x * 64;

  #pragma unroll
  for (int i=0;i<8;i++){
    int c = tid + i*256;
    int row = c >> 5, col = (c & 31) << 3;
    bf16x8 v = ldw8(states + (row0+row)*256 + col);
    *(bf16x8*)&s_x[row*256 + (col ^ ((row&7)<<3))] = v;
  }
  __syncthreads();

  const int wrow = wave*16;
  const int arow = wrow + l15;
  f32x4 acc1[16], acc3[8];
  #pragma unroll
  for (int nt=0;nt<16;nt++){ float bv = fe_b1[nt*16+l15]; acc1[nt] = (f32x4){bv,bv,bv,bv}; }
  #pragma unroll
  for (int nt=0;nt<8;nt++){ float bv = se_b1[nt*16+l15]; acc3[nt] = (f32x4){bv,bv,bv,bv}; }
  #pragma unroll
  for (int kt=0;kt<8;kt++){
    int acol = kt*32 + lh*8;
    bf16x8 af = *(const bf16x8*)&s_x[arow*256 + (acol ^ ((arow&7)<<3))];
    #pragma unroll
    for (int nt=0;nt<16;nt++){
      bf16x8 bw = ldw8(fe_w1 + (nt*16+l15)*256 + acol);
      acc1[nt] = mfma16(af, bw, acc1[nt]);
    }
    #pragma unroll
    for (int nt=0;nt<8;nt++){
      bf16x8 bw = ldw8(se_w1 + (nt*16+l15)*288 + acol);
      acc3[nt] = mfma16(af, bw, acc3[nt]);
    }
  }
  #pragma unroll
  for (int nt=0;nt<8;nt++){
    #pragma unroll
    for (int r=0;r<4;r++){
      int row = wrow + lh*4 + r;
      ws_se1[(row0+row)*128 + nt*16+l15] = f2b(acc3[nt][r]);
    }
  }
  #pragma unroll
  for (int nt=0;nt<16;nt++){
    #pragma unroll
    for (int r=0;r<4;r++){
      int row = wrow + lh*4 + r; int col = nt*16 + l15;
      s_h[row*256 + (col ^ ((row&7)<<3))] = f2b(fgelu(acc1[nt][r]));
    }
  }
  __syncthreads();
  f32x4 acc2[4];
  #pragma unroll
  for (int a=0;a<4;a++){ float bv = fe_b2[a*16+l15]; acc2[a] = (f32x4){bv,bv,bv,bv}; }
  #pragma unroll
  for (int kt=0;kt<8;kt++){
    int acol = kt*32 + lh*8;
    bf16x8 af = *(const bf16x8*)&s_h[arow*256 + (acol ^ ((arow&7)<<3))];
    #pragma unroll
    for (int a=0;a<4;a++){
      bf16x8 bw = ldw8(fe_w2 + (a*16+l15)*256 + acol);
      acc2[a] = mfma16(af, bw, acc2[a]);
    }
  }
  #pragma unroll
  for (int a=0;a<2;a++){
    #pragma unroll
    for (int r=0;r<4;r++){
      int row = wrow + lh*4 + r; int col = a*16 + l15;
      float nfv = nfast[(row0+row)*32 + col];
      float zv = acc2[a][r] + __expf(0.5f*acc2[a+2][r])*nfv;
      ws_zfn[(row0+row)*32 + col] = f2b(zv);
    }
  }
}

// ---------------- K2: recurrence — 128 blocks x 1 wave x 2 batch rows ----------------
// fp32 weights in VGPRs (no unpack, fp32-exact math); shuffle-fed gate combines;
// 4 lfences/step; prefetch floats across steps (no vmcnt drain).
__global__ __launch_bounds__(64,1) void k_rec(
  const u16t* __restrict__ ws_zfn, const u16t* __restrict__ ws_se1,
  const float* __restrict__ actions, const float* __restrict__ noise_slow,
  const float* __restrict__ fg_wih, const float* __restrict__ fg_whh,
  const float* __restrict__ fg_bih, const float* __restrict__ fg_bhh,
  const float* __restrict__ se_w1, const float* __restrict__ se_w2, const float* __restrict__ se_b2,
  const float* __restrict__ sg_wih, const float* __restrict__ sg_whh,
  const float* __restrict__ sg_bih, const float* __restrict__ sg_bhh,
  const float* __restrict__ updp,
  float* __restrict__ out_zf, float* __restrict__ out_zs)
{
  __shared__ __align__(16) float zfnv[2][32], actv[2][4];
  __shared__ __align__(16) float zfv[2][32], zsv[2][16], zsnv[2][16];
  __shared__ __align__(16) float hidv[2][128];
  const int lane = threadIdx.x;
  const int l31 = lane & 31, hf = lane >> 5;
  const long base0 = (long)(2*blockIdx.x    ) * Tn;
  const long base1 = (long)(2*blockIdx.x + 1) * Tn;

  // ---- fp32 weights in VGPRs (shared by both rows) ----
  float wih[36], whh[32], wihH[18], whhH[16], wse[2][32], wsp[64], wsgi[48], wsgh[16];
  #pragma unroll
  for (int k=0;k<36;k++) wih[k] = fg_wih[lane*36+k];
  #pragma unroll
  for (int k=0;k<32;k++) whh[k] = fg_whh[lane*32+k];
  #pragma unroll
  for (int j=0;j<18;j++) wihH[j] = fg_wih[(64+l31)*36 + hf*18 + j];
  #pragma unroll
  for (int j=0;j<16;j++) whhH[j] = fg_whh[(64+l31)*32 + hf*16 + j];
  #pragma unroll
  for (int jj=0;jj<2;jj++){
    #pragma unroll
    for (int k=0;k<32;k++) wse[jj][k] = se_w1[(lane+jj*64)*288 + 256 + k];
  }
  #pragma unroll
  for (int k=0;k<64;k++) wsp[k] = se_w2[l31*128 + hf*64 + k];
  if (lane < 48){
    #pragma unroll
    for (int k=0;k<48;k++) wsgi[k] = sg_wih[lane*48+k];
    #pragma unroll
    for (int k=0;k<16;k++) wsgh[k] = sg_whh[lane*16+k];
  }
  const float bsum  = fg_bih[lane] + fg_bhh[lane];
  const float bni2  = fg_bih[64+l31], bnh2 = fg_bhh[64+l31];
  const float seb2L = se_b2[l31];
  const float sgbiL = sg_bih[lane<48?lane:47], sgbhL = sg_bhh[lane<48?lane:47];
  const float upd = fsigm(updp[0]);

  if (lane < 32){ zfv[0][lane]=0.f; zfv[1][lane]=0.f; }
  if (lane < 16){ zsv[0][lane]=0.f; zsv[1][lane]=0.f; }
  float zf_r[2] = {0.f,0.f};   // lane<32: own zf element per row
  float zs_r[2] = {0.f,0.f};   // lane<16: own zs element per row

  u16t pzfn[2], ps0[2], ps1[2]; float pact[2], pns[2];
  auto pf = [&](int tt){
    if (lane < 32){ pzfn[0]=ws_zfn[(base0+tt)*32+lane]; pzfn[1]=ws_zfn[(base1+tt)*32+lane]; }
    ps0[0]=ws_se1[(base0+tt)*128+lane];    ps0[1]=ws_se1[(base1+tt)*128+lane];
    ps1[0]=ws_se1[(base0+tt)*128+64+lane]; ps1[1]=ws_se1[(base1+tt)*128+64+lane];
    if (lane < 4){ pact[0]=actions[(base0+tt)*4+lane]; pact[1]=actions[(base1+tt)*4+lane]; }
    if (lane < 16){ pns[0]=noise_slow[(base0+tt)*16+lane]; pns[1]=noise_slow[(base1+tt)*16+lane]; }
  };
  pf(0);

  for (int t=0; t<Tn; t++){
    // ---- commit step-t inputs (zfn, act -> LDS; se1/ns -> step-local regs) ----
    float se1a[2], se1c[2], nsq[2];
    #pragma unroll
    for (int q=0;q<2;q++){
      if (lane < 32) zfnv[q][lane] = b2f(pzfn[q]);
      if (lane < 4)  actv[q][lane] = pact[q];
      se1a[q] = b2f(ps0[q]); se1c[q] = b2f(ps1[q]); nsq[q] = pns[q];
    }
    lfence();
    if (t+1 < Tn) pf(t+1);

    // ---- P1: fast GRU (r/z in all lanes; n split across half-waves; shuffle combine) ----
    #pragma unroll
    for (int q=0;q<2;q++){
      float s = bsum;
      #pragma unroll
      for (int p=0;p<8;p++){
        f32x4 x = *(const f32x4*)&zfnv[q][4*p];
        s += wih[4*p]*x[0] + wih[4*p+1]*x[1] + wih[4*p+2]*x[2] + wih[4*p+3]*x[3];
      }
      { f32x4 x = *(const f32x4*)&actv[q][0];
        s += wih[32]*x[0] + wih[33]*x[1] + wih[34]*x[2] + wih[35]*x[3]; }
      #pragma unroll
      for (int p=0;p<8;p++){
        f32x4 x = *(const f32x4*)&zfv[q][4*p];
        s += whh[4*p]*x[0] + whh[4*p+1]*x[1] + whh[4*p+2]*x[2] + whh[4*p+3]*x[3];
      }
      float si = 0.f, sh = 0.f;
      #pragma unroll
      for (int j=0;j<9;j++){
        int k = hf*18 + 2*j;
        const float* xp = (k < 32) ? &zfnv[q][k] : &actv[q][k-32];
        f32x2 xx = *(const f32x2*)xp;
        si += wihH[2*j]*xx[0] + wihH[2*j+1]*xx[1];
      }
      #pragma unroll
      for (int j=0;j<8;j++){
        f32x2 xx = *(const f32x2*)&zfv[q][hf*16 + 2*j];
        sh += whhH[2*j]*xx[0] + whhH[2*j+1]*xx[1];
      }
      si += __shfl_xor(si, 32);
      sh += __shfl_xor(sh, 32);
      float sz = __shfl_xor(s, 32);       // lane o<32 gets z-gate preact
      if (lane < 32){
        float r = fsigm(s);
        float z = fsigm(sz);
        float n = ftanh((si + bni2) + r*(sh + bnh2));
        float h2 = (1.f-z)*n + z*zf_r[q];
        zf_r[q] = h2;
        zfv[q][lane] = h2;
        out_zf[((q?base1:base0)+t)*32 + lane] = h2;
      }
    }
    lfence();
    // ---- P2: slow-encoder hidden (se1 from own regs) ----
    #pragma unroll
    for (int q=0;q<2;q++){
      #pragma unroll
      for (int jj=0;jj<2;jj++){
        float s = jj ? se1c[q] : se1a[q];
        #pragma unroll
        for (int p=0;p<8;p++){
          f32x4 x = *(const f32x4*)&zfv[q][4*p];
          s += wse[jj][4*p]*x[0] + wse[jj][4*p+1]*x[1] + wse[jj][4*p+2]*x[2] + wse[jj][4*p+3]*x[3];
        }
        hidv[q][lane + jj*64] = fgelu(s);
      }
    }
    lfence();
    // ---- P3: sp dots + slow reparam (shuffle-fed) ----
    #pragma unroll
    for (int q=0;q<2;q++){
      float s = 0.f;
      #pragma unroll
      for (int p=0;p<16;p++){
        f32x4 x = *(const f32x4*)&hidv[q][hf*64 + 4*p];
        s += wsp[4*p]*x[0] + wsp[4*p+1]*x[1] + wsp[4*p+2]*x[2] + wsp[4*p+3]*x[3];
      }
      s += __shfl_xor(s, 32);
      float spo = s + seb2L;                       // sp[l31] in every lane
      float sphi = __shfl(spo, (lane+16)&63);      // sp[l31+16]
      if (lane < 16){
        float zn = spo + __expf(0.5f*sphi)*nsq[q];
        zsnv[q][lane] = zn;
      }
    }
    lfence();
    // ---- P4: slow GRU + blend (shuffle combine) ----
    #pragma unroll
    for (int q=0;q<2;q++){
      float gi = sgbiL, gh = sgbhL;
      #pragma unroll
      for (int p=0;p<4;p++){
        f32x4 x = *(const f32x4*)&zsnv[q][4*p];
        gi += wsgi[4*p]*x[0] + wsgi[4*p+1]*x[1] + wsgi[4*p+2]*x[2] + wsgi[4*p+3]*x[3];
      }
      #pragma unroll
      for (int p=0;p<8;p++){
        f32x4 x = *(const f32x4*)&zfv[q][4*p];
        gi += wsgi[16+4*p]*x[0] + wsgi[16+4*p+1]*x[1] + wsgi[16+4*p+2]*x[2] + wsgi[16+4*p+3]*x[3];
      }
      #pragma unroll
      for (int p=0;p<4;p++){
        f32x4 x = *(const f32x4*)&zsv[q][4*p];
        gh += wsgh[4*p]*x[0] + wsgh[4*p+1]*x[1] + wsgh[4*p+2]*x[2] + wsgh[4*p+3]*x[3];
      }
      float gi_z = __shfl(gi, (lane+16)&63), gi_n = __shfl(gi, (lane+32)&63);
      float gh_z = __shfl(gh, (lane+16)&63), gh_n = __shfl(gh, (lane+32)&63);
      if (lane < 16){
        float r = fsigm(gi + gh);
        float z = fsigm(gi_z + gh_z);
        float n = ftanh(gi_n + r*gh_n);
        float zt = (1.f-z)*n + z*zs_r[q];
        float zn = upd*zt + (1.f-upd)*zs_r[q];
        zs_r[q] = zn;
        zsv[q][lane] = zn;
        out_zs[((q?base1:base0)+t)*16 + lane] = zn;
      }
    }
    // no trailing fence: next iter's commit fence orders zsv/zfv for P1/P4 reads
  }
}

// ---------------- K3: MFMA decoder, 64 rows/block, fp32 in/out ----------------
__global__ __launch_bounds__(256) void k_dec(
  const float* __restrict__ izf, const float* __restrict__ izs,
  const float* __restrict__ de_w1, const float* __restrict__ de_b1,
  const float* __restrict__ de_w2, const float* __restrict__ de_b2,
  float* __restrict__ preds)
{
  __shared__ __align__(16) u16t s_a[64*64];
  __shared__ __align__(16) u16t s_h[64*256];
  const int tid = threadIdx.x;
  const int lane = tid & 63, wave = tid >> 6;
  const int l15 = lane & 15, lh = lane >> 4;
  const long row0 = (long)blockIdx.x * 64;

  { int row = tid >> 2, col = (tid & 3) << 3;
    bf16x8 v = ldw8(izf + (row0+row)*32 + col);
    *(bf16x8*)&s_a[row*64 + (col ^ ((row&7)<<3))] = v; }
  if (tid < 128){
    int row = tid >> 1, col = 32 + ((tid & 1) << 3);
    bf16x8 v = ldw8(izs + (row0+row)*16 + ((tid&1)<<3));
    *(bf16x8*)&s_a[row*64 + (col ^ ((row&7)<<3))] = v;
  } else {
    int t2 = tid - 128;
    int row = t2 >> 1, col = 48 + ((t2 & 1) << 3);
    bf16x8 v = zero8();
    *(bf16x8*)&s_a[row*64 + (col ^ ((row&7)<<3))] = v;
  }
  __syncthreads();

  const int wrow = wave*16;
  const int arow = wrow + l15;
  f32x4 acc[16];
  #pragma unroll
  for (int nt=0;nt<16;nt++){ float bv = de_b1[nt*16+l15]; acc[nt] = (f32x4){bv,bv,bv,bv}; }
  #pragma unroll
  for (int kt=0;kt<2;kt++){
    int acol = kt*32 + lh*8;
    bf16x8 af = *(const bf16x8*)&s_a[arow*64 + (acol ^ ((arow&7)<<3))];
    #pragma unroll
    for (int nt=0;nt<16;nt++){
      bf16x8 bw = zero8();
      if (!(kt==1 && lh>=2)) bw = ldw8(de_w1 + (nt*16+l15)*48 + acol);
      acc[nt] = mfma16(af, bw, acc[nt]);
    }
  }
  #pragma unroll
  for (int nt=0;nt<16;nt++){
    #pragma unroll
    for (int r=0;r<4;r++){
      int row = wrow + lh*4 + r; int col = nt*16 + l15;
      s_h[row*256 + (col ^ ((row&7)<<3))] = f2b(fgelu(acc[nt][r]));
    }
  }
  __syncthreads();
  f32x4 a2[16];
  #pragma unroll
  for (int nt=0;nt<16;nt++){ float bv = de_b2[nt*16+l15]; a2[nt] = (f32x4){bv,bv,bv,bv}; }
  #pragma unroll
  for (int kt=0;kt<8;kt++){
    int acol = kt*32 + lh*8;
    bf16x8 af = *(const bf16x8*)&s_h[arow*256 + (acol ^ ((arow&7)<<3))];
    #pragma unroll
    for (int nt=0;nt<16;nt++){
      bf16x8 bw = ldw8(de_w2 + (nt*16+l15)*256 + acol);
      a2[nt] = mfma16(af, bw, a2[nt]);
    }
  }
  #pragma unroll
  for (int nt=0;nt<16;nt++){
    #pragma unroll
    for (int r=0;r<4;r++){
      int row = wrow + lh*4 + r;
      preds[(row0+row)*256 + nt*16+l15] = a2[nt][r];
    }
  }
}

extern "C" void kernel_launch(void* const* d_in, const int* in_sizes, int n_in,
                              void* d_out, int out_size, void* d_ws, size_t ws_size,
                              hipStream_t stream)
{
  if (n_in < 25 || in_sizes[0] != (int)(Rn*256) || in_sizes[8] != 96*36 ||
      in_sizes[12] != 128*288 || in_sizes[20] != 256*48 || in_sizes[24] != 1)
    return;
  if (out_size != (int)(Rn*304))
    return;

  const float* states = (const float*)d_in[0];
  const float* actions= (const float*)d_in[1];
  const float* nfast  = (const float*)d_in[2];
  const float* nslow  = (const float*)d_in[3];
  const float* fe_w1  = (const float*)d_in[4];
  const float* fe_b1  = (const float*)d_in[5];
  const float* fe_w2  = (const float*)d_in[6];
  const float* fe_b2  = (const float*)d_in[7];
  const float* fg_wih = (const float*)d_in[8];
  const float* fg_whh = (const float*)d_in[9];
  const float* fg_bih = (const float*)d_in[10];
  const float* fg_bhh = (const float*)d_in[11];
  const float* se_w1  = (const float*)d_in[12];
  const float* se_b1  = (const float*)d_in[13];
  const float* se_w2  = (const float*)d_in[14];
  const float* se_b2  = (const float*)d_in[15];
  const float* sg_wih = (const float*)d_in[16];
  const float* sg_whh = (const float*)d_in[17];
  const float* sg_bih = (const float*)d_in[18];
  const float* sg_bhh = (const float*)d_in[19];
  const float* de_w1  = (const float*)d_in[20];
  const float* de_b1  = (const float*)d_in[21];
  const float* de_w2  = (const float*)d_in[22];
  const float* de_b2  = (const float*)d_in[23];
  const float* updp   = (const float*)d_in[24];

  // d_out is FP32: [preds | zf | zs] flat.
  float* preds = (float*)d_out;
  float* ozf = preds + Rn*256;
  float* ozs = ozf + Rn*32;

  // Scratch: zfn bf16 [Rn][32] + se1 bf16 [Rn][128] = Rn*320 bytes.
  size_t need = (size_t)Rn*320;
  u16t* ws_zfn; u16t* ws_se1;
  if (ws_size >= need){
    ws_zfn = (u16t*)d_ws;
    ws_se1 = ws_zfn + Rn*32;
  } else {
    ws_zfn = (u16t*)preds;   // alias inside preds fp32 region; k_dec overwrites after
    ws_se1 = ws_zfn + Rn*32;
  }

  k_pre<<<(int)(Rn/64), 256, 0, stream>>>(states, nfast,
      fe_w1, fe_b1, fe_w2, fe_b2, se_w1, se_b1, ws_zfn, ws_se1);
  k_rec<<<Bn/2, 64, 0, stream>>>(ws_zfn, ws_se1, actions, nslow,
      fg_wih, fg_whh, fg_bih, fg_bhh, se_w1, se_w2, se_b2,
      sg_wih, sg_whh, sg_bih, sg_bhh, updp, ozf, ozs);
  k_dec<<<(int)(Rn/64), 256, 0, stream>>>(ozf, ozs, de_w1, de_b1, de_w2, de_b2, preds);
}